// Round 4
// baseline (457.335 us; speedup 1.0000x reference)
//
#include <hip/hip_runtime.h>

// LengthRegulator: B=64, C=384, T=512 -> MAX_NEW_TIME=4096
// dur[b,t] in [0,8). csum = inclusive scan. Frame t owns output positions
// [csum[t-1], csum[t]). Positions >= total read sentinel (zero). Mask =
// (out[b,0,j] != 0).

#define BB 64
#define CC 384
#define TT 512
#define TOUT 4096
#define CB 16          // channels per tile: 16 rows
#define ROW4 129       // row stride in float4 (128 data + 1 zero pad)
#define ROWF (ROW4*4)  // row stride in floats = 516; sentinel idx = 512
#define TILES_PER_BLK 2

// Kernel 1: per-batch scan of durations + scatter of frame index.
// idx[b*TOUT + j] = t such that csum[t-1] <= j < csum[t], else 512 (sentinel
// pointing at the zeroed LDS pad slot in the gather kernel).
__global__ __launch_bounds__(TT) void build_idx_kernel(
    const int* __restrict__ dur, int* __restrict__ idx) {
  const int b = blockIdx.x;
  const int t = threadIdx.x;

  __shared__ int s[TT];
  const int d = dur[b * TT + t];
  s[t] = d;
  __syncthreads();

  // Hillis-Steele inclusive scan over 512 elements (9 steps)
  for (int off = 1; off < TT; off <<= 1) {
    int v = (t >= off) ? s[t - off] : 0;
    __syncthreads();
    s[t] += v;
    __syncthreads();
  }

  const int end = s[t];
  const int start = end - d;

  int* __restrict__ idxb = idx + b * TOUT;
  #pragma unroll
  for (int k = 0; k < TOUT / TT; ++k) idxb[t + k * TT] = TT;  // sentinel
  __syncthreads();

  // Scatter: segments are disjoint, at most 7 writes per thread
  for (int p = start; p < end; ++p) idxb[p] = t;
}

// Kernel 2: LDS-staged expand-gather, balanced persistent grid.
// grid = (C/CB/2, B) = (12, 64) = 768 blocks = exactly 3/CU (96 KB LDS,
// 12 waves/CU) -> no tail round. Each block: loads its 16 idx values once
// into registers, then processes 2 channel-tiles of the same batch.
// LDS rows padded to 516 floats with row[512..515]=0 so sentinel index 512
// yields 0.0f without any compare/select in the inner loop.
__global__ __launch_bounds__(256) void gather_kernel(
    const float* __restrict__ x, const int* __restrict__ idx,
    float* __restrict__ out, float* __restrict__ mask) {
  const int b = blockIdx.y;
  const int tid = threadIdx.x;

  __shared__ float xs[CB * ROWF];  // 16 rows x 516 floats = 33024 B

  // This thread's 16 output positions (4 per j-tile of 1024), loaded once.
  const int4* __restrict__ ib4 = (const int4*)(idx + (size_t)b * TOUT);
  int4 I[TOUT / 1024];
  #pragma unroll
  for (int jt = 0; jt < TOUT / 1024; ++jt)
    I[jt] = ib4[jt * 256 + tid];

  float4* __restrict__ xs4 = (float4*)xs;

  #pragma unroll
  for (int s = 0; s < TILES_PER_BLK; ++s) {
    const int c0 = (blockIdx.x * TILES_PER_BLK + s) * CB;

    // Stage x tile: 2048 data float4s, coalesced, row-remapped to stride 129.
    const float4* __restrict__ xb4 =
        (const float4*)(x + ((size_t)b * CC + c0) * TT);
    #pragma unroll
    for (int k = 0; k < (CB * TT / 4) / 256; ++k) {
      const int k2 = k * 256 + tid;
      const int row = k2 >> 7;       // /128
      const int col = k2 & 127;
      xs4[row * ROW4 + col] = xb4[k2];
    }
    // Zero the pad slot of each row (sentinel target).
    if (tid < CB) xs4[tid * ROW4 + 128] = make_float4(0.f, 0.f, 0.f, 0.f);
    __syncthreads();

    float* __restrict__ ob = out + ((size_t)b * CC + c0) * TOUT + tid * 4;

    #pragma unroll
    for (int c = 0; c < CB; ++c) {
      const float* __restrict__ xr = xs + c * ROWF;
      #pragma unroll
      for (int jt = 0; jt < TOUT / 1024; ++jt) {
        const int4 i4 = I[jt];
        float4 v;
        v.x = xr[i4.x];
        v.y = xr[i4.y];
        v.z = xr[i4.z];
        v.w = xr[i4.w];
        *(float4*)(ob + (size_t)c * TOUT + jt * 1024) = v;

        if (c == 0 && c0 == 0) {
          float4 m;
          m.x = (v.x != 0.0f) ? 1.0f : 0.0f;
          m.y = (v.y != 0.0f) ? 1.0f : 0.0f;
          m.z = (v.z != 0.0f) ? 1.0f : 0.0f;
          m.w = (v.w != 0.0f) ? 1.0f : 0.0f;
          *(float4*)(mask + (size_t)b * TOUT + jt * 1024 + tid * 4) = m;
        }
      }
    }
    __syncthreads();  // LDS reuse hazard before restaging next tile
  }
}

extern "C" void kernel_launch(void* const* d_in, const int* in_sizes, int n_in,
                              void* d_out, int out_size, void* d_ws, size_t ws_size,
                              hipStream_t stream) {
  const float* x = (const float*)d_in[0];       // (B, C, T) f32
  const int* dur = (const int*)d_in[1];         // (B, 1, T) i32

  float* out = (float*)d_out;                   // (B, C, TOUT) f32
  float* mask = out + (size_t)BB * CC * TOUT;   // (B, 1, TOUT), written as f32 0/1

  int* idx = (int*)d_ws;                        // (B, TOUT) i32 = 1 MB

  build_idx_kernel<<<BB, TT, 0, stream>>>(dur, idx);
  gather_kernel<<<dim3(CC / CB / TILES_PER_BLK, BB), 256, 0, stream>>>(
      x, idx, out, mask);
}

// Round 5
// 434.751 us; speedup vs baseline: 1.0519x; 1.0519x over previous
//
#include <hip/hip_runtime.h>

// LengthRegulator: B=64, C=384, T=512 -> MAX_NEW_TIME=4096
// dur[b,t] in [0,8). csum = inclusive scan. Frame t owns output positions
// [csum[t-1], csum[t]). Positions >= total read sentinel (zero). Mask =
// (out[b,0,j] != 0).

#define BB 64
#define CC 384
#define TT 512
#define TOUT 4096
#define CB 8           // channels per tile: 8 rows -> 16.5 KB LDS
#define ROW4 129       // row stride in float4 (128 data + 1 zero pad)
#define ROWF (ROW4*4)  // row stride floats = 516; row bytes = 2064
#define TILES_PER_BLK 2

// Kernel 1: per-batch scan of durations + scatter of frame index.
// idx[b*TOUT + j] = t such that csum[t-1] <= j < csum[t], else 512 (sentinel
// pointing at the zeroed LDS pad slot in the gather kernel).
__global__ __launch_bounds__(TT) void build_idx_kernel(
    const int* __restrict__ dur, int* __restrict__ idx) {
  const int b = blockIdx.x;
  const int t = threadIdx.x;

  __shared__ int s[TT];
  const int d = dur[b * TT + t];
  s[t] = d;
  __syncthreads();

  // Hillis-Steele inclusive scan over 512 elements (9 steps)
  for (int off = 1; off < TT; off <<= 1) {
    int v = (t >= off) ? s[t - off] : 0;
    __syncthreads();
    s[t] += v;
    __syncthreads();
  }

  const int end = s[t];
  const int start = end - d;

  int* __restrict__ idxb = idx + b * TOUT;
  #pragma unroll
  for (int k = 0; k < TOUT / TT; ++k) idxb[t + k * TT] = TT;  // sentinel
  __syncthreads();

  // Scatter: segments are disjoint, at most 7 writes per thread
  for (int p = start; p < end; ++p) idxb[p] = t;
}

// Kernel 2: LDS-staged expand-gather.
// grid = (C/(CB*2), B) = (24, 64) = 1536 blocks = exactly 6 resident/CU
// (6 x 16.5 KB = 99 KB LDS, 24 waves/CU). Indices pre-scaled to byte
// offsets so inner LDS reads are vaddr + ds_read imm offset (c*2064) with
// no per-element VALU. Sentinel byte-offset 2048 hits the zeroed pad.
__global__ __launch_bounds__(256) void gather_kernel(
    const float* __restrict__ x, const int* __restrict__ idx,
    float* __restrict__ out, float* __restrict__ mask) {
  const int b = blockIdx.y;
  const int tid = threadIdx.x;

  __shared__ float xs[CB * ROWF];  // 8 x 516 floats = 16512 B

  // This thread's 16 output positions as LDS byte offsets, loaded once.
  const int4* __restrict__ ib4 = (const int4*)(idx + (size_t)b * TOUT);
  int4 O[TOUT / 1024];
  #pragma unroll
  for (int jt = 0; jt < TOUT / 1024; ++jt) {
    int4 i4 = ib4[jt * 256 + tid];
    O[jt].x = i4.x << 2;
    O[jt].y = i4.y << 2;
    O[jt].z = i4.z << 2;
    O[jt].w = i4.w << 2;
  }

  float4* __restrict__ xs4 = (float4*)xs;
  const char* __restrict__ xsb = (const char*)xs;

  #pragma unroll
  for (int s = 0; s < TILES_PER_BLK; ++s) {
    const int c0 = (blockIdx.x * TILES_PER_BLK + s) * CB;

    // Stage x tile: 1024 data float4s, coalesced, row-remapped to stride 129.
    const float4* __restrict__ xb4 =
        (const float4*)(x + ((size_t)b * CC + c0) * TT);
    #pragma unroll
    for (int k = 0; k < (CB * TT / 4) / 256; ++k) {
      const int k2 = k * 256 + tid;
      const int row = k2 >> 7;       // /128
      const int col = k2 & 127;
      xs4[row * ROW4 + col] = xb4[k2];
    }
    // Zero the pad slot of each row (sentinel target, float index 512).
    if (tid < CB) xs4[tid * ROW4 + 128] = make_float4(0.f, 0.f, 0.f, 0.f);
    __syncthreads();

    float* __restrict__ ob = out + ((size_t)b * CC + c0) * TOUT + tid * 4;

    #pragma unroll
    for (int c = 0; c < CB; ++c) {
      const char* __restrict__ xrc = xsb + c * (ROWF * 4);  // imm-foldable
      #pragma unroll
      for (int jt = 0; jt < TOUT / 1024; ++jt) {
        const int4 o = O[jt];
        float4 v;
        v.x = *(const float*)(xrc + o.x);
        v.y = *(const float*)(xrc + o.y);
        v.z = *(const float*)(xrc + o.z);
        v.w = *(const float*)(xrc + o.w);
        *(float4*)(ob + (size_t)c * TOUT + jt * 1024) = v;

        if (c == 0 && c0 == 0) {
          float4 m;
          m.x = (v.x != 0.0f) ? 1.0f : 0.0f;
          m.y = (v.y != 0.0f) ? 1.0f : 0.0f;
          m.z = (v.z != 0.0f) ? 1.0f : 0.0f;
          m.w = (v.w != 0.0f) ? 1.0f : 0.0f;
          *(float4*)(mask + (size_t)b * TOUT + jt * 1024 + tid * 4) = m;
        }
      }
    }
    __syncthreads();  // LDS reuse hazard before restaging next tile
  }
}

extern "C" void kernel_launch(void* const* d_in, const int* in_sizes, int n_in,
                              void* d_out, int out_size, void* d_ws, size_t ws_size,
                              hipStream_t stream) {
  const float* x = (const float*)d_in[0];       // (B, C, T) f32
  const int* dur = (const int*)d_in[1];         // (B, 1, T) i32

  float* out = (float*)d_out;                   // (B, C, TOUT) f32
  float* mask = out + (size_t)BB * CC * TOUT;   // (B, 1, TOUT), written as f32 0/1

  int* idx = (int*)d_ws;                        // (B, TOUT) i32 = 1 MB

  build_idx_kernel<<<BB, TT, 0, stream>>>(dur, idx);
  gather_kernel<<<dim3(CC / CB / TILES_PER_BLK, BB), 256, 0, stream>>>(
      x, idx, out, mask);
}